// Round 12
// baseline (136.015 us; speedup 1.0000x reference)
//
#include <hip/hip_runtime.h>
#include <math.h>

#define NB 32
#define NT 512
#define NS 64
#define NOBS 4
#define NEMB 32
#define NPE 16
#define NATTN 10
#define ND 26  // ATTN + PE

typedef _Float16 half2_t __attribute__((ext_vector_type(2)));

// pack two f32 -> one dword of two f16 (scalar cvt; no wide ext-vectors)
__device__ __forceinline__ unsigned pkh(float a, float b) {
    _Float16 ha = (_Float16)a, hb = (_Float16)b;
    unsigned short ua, ub;
    __builtin_memcpy(&ua, &ha, 2);
    __builtin_memcpy(&ub, &hb, 2);
    return (unsigned)ua | ((unsigned)ub << 16);
}

__device__ __forceinline__ float2 unpack_h2(unsigned u) {
    unsigned short l16 = (unsigned short)(u & 0xffffu);
    unsigned short h16 = (unsigned short)(u >> 16);
    _Float16 lo, hi;
    __builtin_memcpy(&lo, &l16, 2);
    __builtin_memcpy(&hi, &h16, 2);
    return make_float2((float)lo, (float)hi);
}

// c += dot(two f16 pairs): single v_dot2_f32_f16 (no unpack VALU)
__device__ __forceinline__ float dot2h(unsigned a, unsigned b, float c) {
#if __has_builtin(__builtin_amdgcn_fdot2)
    return __builtin_amdgcn_fdot2(__builtin_bit_cast(half2_t, a),
                                  __builtin_bit_cast(half2_t, b), c, false);
#else
    float2 fa = unpack_h2(a), fb = unpack_h2(b);
    return c + fa.x * fb.x + fa.y * fb.y;
#endif
}

// f16 obsW tile: row s = 16 chunks x 16B; chunk c = eb*2 + opair,
// XOR-swizzled so 8 consecutive lanes hit 8 distinct bank-quads.
__device__ __forceinline__ int obs16_off(int s, int c) {  // byte offset
    return (s << 8) + (((c ^ (s & 7)) & 15) << 4);
}

__global__ __launch_bounds__(512, 8)   // pin VGPR <= 64: 8 waves/SIMD (R11 lesson)
void raindrop_kernel(const float* __restrict__ x,
                     const float* __restrict__ times,
                     const float* __restrict__ mask,
                     const float* __restrict__ obsW,
                     const float* __restrict__ attnW,
                     const float* __restrict__ recvW,
                     const float* __restrict__ recvB,
                     float* __restrict__ out)
{
    // 33 KiB total -> 4 blocks/CU, 32 waves/CU. hq region is SEPARATE from
    // the obsW tile -> obsW never overwritten -> only ONE barrier in kernel.
    __shared__ unsigned obsw16[NS * 64];    // 16 KiB f16-packed obsW
    __shared__ unsigned hq_lds[8 * NS * 8]; // 16 KiB packed hq rows (32B/row)
    __shared__ float wpe[8 * NEMB];         // 1 KiB per-wave folded-PE strips

    const int tid = threadIdx.x;

    // Stage obsW as packed f16. Thread t handles (s = t>>3, eb = t&7):
    // 4 coalesced float4 loads (one per o), 8 pkh, 2 swizzled b128 writes.
    {
        const int s0 = tid >> 3, eb0 = tid & 7;
        const float* src = obsW + s0 * 128 + eb0 * 4;
        float4 w0 = *reinterpret_cast<const float4*>(src);
        float4 w1 = *reinterpret_cast<const float4*>(src + 32);
        float4 w2 = *reinterpret_cast<const float4*>(src + 64);
        float4 w3 = *reinterpret_cast<const float4*>(src + 96);
        uint4 ca, cb;  // chunk A: o-pair(0,1), chunk B: o-pair(2,3)
        ca.x = pkh(w0.x, w1.x); ca.y = pkh(w0.y, w1.y);
        ca.z = pkh(w0.z, w1.z); ca.w = pkh(w0.w, w1.w);
        cb.x = pkh(w2.x, w3.x); cb.y = pkh(w2.y, w3.y);
        cb.z = pkh(w2.z, w3.z); cb.w = pkh(w2.w, w3.w);
        char* base = reinterpret_cast<char*>(obsw16);
        *reinterpret_cast<uint4*>(base + obs16_off(s0, eb0 * 2 + 0)) = ca;
        *reinterpret_cast<uint4*>(base + obs16_off(s0, eb0 * 2 + 1)) = cb;
    }

    const int lane = tid & 63;
    const int wv = tid >> 6;
    const int bt = blockIdx.x * 8 + wv;   // one wave per (b,t)
    const int s = lane;                   // phase-1 role: lane = sensor
    const int g = lane >> 4;              // phase-3 row group (4 x 16)
    const int iu = lane & 15;             // phase-3 u-quad owner

    // per-lane attnW quad, PACKED f16: 4 u x 5 dwords = 20 VGPRs (was 40)
    unsigned awp[4][5];
    {
        const float2* ap = reinterpret_cast<const float2*>(attnW + (iu * 4) * NATTN);
#pragma unroll
        for (int j = 0; j < 4; ++j)
#pragma unroll
            for (int q = 0; q < 5; ++q) {
                float2 v = ap[j * 5 + q];
                awp[j][q] = pkh(v.x, v.y);
            }
    }

    // positional encoding (wave-uniform; div[i] = 10^(-i/2)); native sin/cos
    const float tt = times[bt];
    const float divs[8] = {1.0f, 0.31622776601683794f, 0.1f, 0.031622776601683794f,
                           0.01f, 0.0031622776601683794f, 0.001f, 0.00031622776601683794f};
    float pe[NPE];
#pragma unroll
    for (int i = 0; i < 8; ++i) {
        float ang = tt * divs[i];
        pe[2 * i]     = __sinf(ang);
        pe[2 * i + 1] = __cosf(ang);
    }

    // c0 = recvB[10:26] . pe  (uniform; recvB via s_load)
    float c0 = 0.f;
#pragma unroll
    for (int p = 0; p < NPE; ++p) c0 += recvB[NATTN + p] * pe[p];

    // w_pe: lane e (= lane&31) folds recvW[e][10..25] with pe -> LDS strip.
    // Same-wave write->read later; ordered before the barrier anyway.
    float* wpw = &wpe[wv * NEMB];
    {
        const int e = lane & 31;
        const float2* rp = reinterpret_cast<const float2*>(recvW + e * ND + NATTN);
        float acc = 0.f;
#pragma unroll
        for (int p2 = 0; p2 < 8; ++p2) {
            float2 w = rp[p2];
            acc += w.x * pe[2 * p2];
            acc += w.y * pe[2 * p2 + 1];
        }
        if (lane < NEMB) wpw[e] = acc;
    }

    // per-lane inputs (coalesced: 64 lanes x 16B contiguous); pack x to f16
    const float4 xv = *reinterpret_cast<const float4*>(x + ((size_t)bt * NS + s) * NOBS);
    const float  mv = mask[(size_t)bt * NS + s];
    const unsigned x01 = pkh(xv.x, xv.y);
    const unsigned x23 = pkh(xv.z, xv.w);

    __syncthreads();  // obsW tile ready — the ONLY barrier in the kernel

    // hq[a] = recv_b[a] + sum_e h_e * recv_W[e][a]   (a = 0..9 only)
    // beta' = sum_e h_e * w_pe[e]
    float hq[NATTN];
#pragma unroll
    for (int a = 0; a < NATTN; ++a) hq[a] = recvB[a];  // uniform -> s_load
    float betah = 0.f;

    const char* wrow = reinterpret_cast<const char*>(obsw16) + (s << 8);
    const int sx = s & 7;

#pragma unroll
    for (int eb = 0; eb < 8; ++eb) {  // e = eb*4 + j
        // 2 swizzled b128: chunk A (o0,o1 pairs), chunk B (o2,o3 pairs)
        uint4 wa = *reinterpret_cast<const uint4*>(wrow + ((((eb << 1) | 0) ^ sx) << 4));
        uint4 wb = *reinterpret_cast<const uint4*>(wrow + ((((eb << 1) | 1) ^ sx) << 4));
        float a0 = dot2h(x23, wb.x, dot2h(x01, wa.x, 0.f));
        float a1 = dot2h(x23, wb.y, dot2h(x01, wa.y, 0.f));
        float a2 = dot2h(x23, wb.z, dot2h(x01, wa.z, 0.f));
        float a3 = dot2h(x23, wb.w, dot2h(x01, wa.w, 0.f));
        const float h0 = fmaxf(a0, 0.f) * mv;
        const float h1 = fmaxf(a1, 0.f) * mv;
        const float h2 = fmaxf(a2, 0.f) * mv;
        const float h3 = fmaxf(a3, 0.f) * mv;

        // beta' contribution: uniform ds_read_b128 broadcast of 4 w_pe
        float4 wp = *reinterpret_cast<const float4*>(wpw + eb * 4);
        betah += h0 * wp.x + h1 * wp.y + h2 * wp.z + h3 * wp.w;

        const float* rw = recvW + (eb * 4) * ND;  // uniform base -> s_load
#pragma unroll
        for (int a = 0; a < NATTN; ++a) {
            hq[a] += h0 * rw[a] + h1 * rw[ND + a] + h2 * rw[2 * ND + a] + h3 * rw[3 * ND + a];
        }
    }

    const float beta = c0 + betah;

    // Stage this wave's hq row, PACKED f16 (+f32 beta): 32B stride.
    // Same-wave write->read (in-order DS, proven R5-R8); no barrier.
    unsigned* hbase = &hq_lds[wv * (NS * 8)];
    {
        unsigned* hrow = hbase + s * 8;
        uint4 rA;
        rA.x = pkh(hq[0], hq[1]); rA.y = pkh(hq[2], hq[3]);
        rA.z = pkh(hq[4], hq[5]); rA.w = pkh(hq[6], hq[7]);
        uint2 rB;
        rB.x = pkh(hq[8], hq[9]);
        rB.y = __builtin_bit_cast(unsigned, beta);
        *reinterpret_cast<uint4*>(hrow)     = rA;
        *reinterpret_cast<uint2*>(hrow + 4) = rB;
    }

    // Phase 3: 4 row-groups x 16 lanes (R8 grouping, VGPR-safe). Per iter:
    // b128 + b64 at 4 distinct 32B-strided addrs (bank-quads {0,8,16,24} /
    // {4,12,20,28}: conflict-free broadcast), 20 fdot2/lane, one coalesced
    // 1KB wave store (4 rows x 256B).
    const unsigned* hg = hbase + g * 8;
    float* optr = out + (size_t)bt * (NS * NS) + g * NS + iu * 4;
#pragma unroll 4
    for (int r = 0; r < NS; r += 4) {
        const unsigned* hr = hg + r * 8;
        uint4 A = *reinterpret_cast<const uint4*>(hr);
        uint2 Bv = *reinterpret_cast<const uint2*>(hr + 4);
        const float beta_r = __builtin_bit_cast(float, Bv.y);
        float4 rv;
#pragma unroll
        for (int j = 0; j < 4; ++j) {
            float acc = beta_r;
            acc = dot2h(A.x, awp[j][0], acc);
            acc = dot2h(A.y, awp[j][1], acc);
            acc = dot2h(A.z, awp[j][2], acc);
            acc = dot2h(A.w, awp[j][3], acc);
            acc = dot2h(Bv.x, awp[j][4], acc);
            (&rv.x)[j] = fmaxf(acc, 0.f);
        }
        *reinterpret_cast<float4*>(optr) = rv;
        optr += 4 * NS;
    }
}

extern "C" void kernel_launch(void* const* d_in, const int* in_sizes, int n_in,
                              void* d_out, int out_size, void* d_ws, size_t ws_size,
                              hipStream_t stream) {
    const float* x     = (const float*)d_in[0];
    const float* times = (const float*)d_in[1];
    const float* mask  = (const float*)d_in[2];
    const float* obsW  = (const float*)d_in[3];
    const float* attnW = (const float*)d_in[4];
    const float* recvW = (const float*)d_in[5];
    const float* recvB = (const float*)d_in[6];
    float* out = (float*)d_out;

    // B*T = 16384 (b,t) pairs, one wave each, 8 waves per block
    raindrop_kernel<<<dim3((NB * NT) / 8), dim3(512), 0, stream>>>(
        x, times, mask, obsW, attnW, recvW, recvB, out);
}

// Round 13
// 71.383 us; speedup vs baseline: 1.9054x; 1.9054x over previous
//
#include <hip/hip_runtime.h>
#include <math.h>

#define NB 32
#define NT 512
#define NS 64
#define NOBS 4
#define NEMB 32
#define NPE 16
#define NATTN 10
#define ND 26  // ATTN + PE

// obs_emb_weights LDS layout: 64 rows (sensor s) x 128 dwords (o*32+e),
// 16B-chunk XOR swizzle so per-lane ds_read_b128 of row s spreads banks.
__device__ __forceinline__ int obs_idx(int s, int chunk) {
    return (s << 7) + (((chunk ^ (s & 7)) & 31) << 2);
}

// pack two f32 -> one dword of two f16 (scalar cvt; proven R7 path)
__device__ __forceinline__ unsigned pkh(float a, float b) {
    _Float16 ha = (_Float16)a, hb = (_Float16)b;
    unsigned short ua, ub;
    __builtin_memcpy(&ua, &ha, 2);
    __builtin_memcpy(&ub, &hb, 2);
    return (unsigned)ua | ((unsigned)ub << 16);
}

// unpack dword of two f16 -> float2 (proven R4/R7 path)
__device__ __forceinline__ float2 unpack_h2(unsigned u) {
    unsigned short l16 = (unsigned short)(u & 0xffffu);
    unsigned short h16 = (unsigned short)(u >> 16);
    _Float16 lo, hi;
    __builtin_memcpy(&lo, &l16, 2);
    __builtin_memcpy(&hi, &h16, 2);
    return make_float2((float)lo, (float)hi);
}

__global__ __launch_bounds__(512)
void raindrop_kernel(const float* __restrict__ x,
                     const float* __restrict__ times,
                     const float* __restrict__ mask,
                     const float* __restrict__ obsW,
                     const float* __restrict__ attnW,
                     const float* __restrict__ recvW,
                     const float* __restrict__ recvB,
                     float* __restrict__ out)
{
    // 49 KiB total -> 3 blocks/CU (24 waves). obsW tile is NEVER overwritten
    // -> exactly ONE barrier; after it, every wave free-runs to the end
    // (hq16/wpe are same-wave write->read only). Waves desync -> stores mix
    // with other waves' phase-1 instead of device-wide bursts.
    __shared__ float obsw_lds[NS * 128];     // 32 KiB f32 swizzled obsW
    __shared__ unsigned hq16[8 * NS * 8];    // 16 KiB packed hq rows (32B/row)
    __shared__ float wpe[8 * NEMB];          // 1 KiB per-wave folded-PE strips

    const int tid = threadIdx.x;

    // Stage S*OBS*EMB = 8192 floats (coalesced float4 reads, swizzled writes)
#pragma unroll
    for (int k = 0; k < 4; ++k) {
        int i = (tid << 2) + (k << 11);
        float4 v = *reinterpret_cast<const float4*>(obsW + i);
        *reinterpret_cast<float4*>(&obsw_lds[obs_idx(i >> 7, (i & 127) >> 2)]) = v;
    }

    const int lane = tid & 63;
    const int wv = tid >> 6;
    const int bt = blockIdx.x * 8 + wv;   // one wave per (b,t)
    const int s = lane;                   // phase-1 role: lane = sensor
    const int g = lane >> 4;              // phase-3 row group (4 x 16)
    const int iu = lane & 15;             // phase-3 u-quad owner

    // per-lane attnW quad for phase 3 (40 f32 VGPRs — R8-proven budget)
    float aw0[NATTN], aw1[NATTN], aw2[NATTN], aw3[NATTN];
    {
        const float2* ap = reinterpret_cast<const float2*>(attnW + (iu * 4) * NATTN);
#pragma unroll
        for (int q = 0; q < 5; ++q) {
            float2 v0 = ap[q];      aw0[2*q] = v0.x; aw0[2*q+1] = v0.y;
            float2 v1 = ap[5 + q];  aw1[2*q] = v1.x; aw1[2*q+1] = v1.y;
            float2 v2 = ap[10 + q]; aw2[2*q] = v2.x; aw2[2*q+1] = v2.y;
            float2 v3 = ap[15 + q]; aw3[2*q] = v3.x; aw3[2*q+1] = v3.y;
        }
    }

    // positional encoding (wave-uniform; div[i] = 10^(-i/2)); native sin/cos
    const float tt = times[bt];
    const float divs[8] = {1.0f, 0.31622776601683794f, 0.1f, 0.031622776601683794f,
                           0.01f, 0.0031622776601683794f, 0.001f, 0.00031622776601683794f};
    float pe[NPE];
#pragma unroll
    for (int i = 0; i < 8; ++i) {
        float ang = tt * divs[i];
        pe[2 * i]     = __sinf(ang);
        pe[2 * i + 1] = __cosf(ang);
    }

    // c0 = recvB[10:26] . pe  (uniform; recvB via s_load)
    float c0 = 0.f;
#pragma unroll
    for (int p = 0; p < NPE; ++p) c0 += recvB[NATTN + p] * pe[p];

    // w_pe: lane e (= lane&31) folds recvW[e][10..25] with pe -> LDS strip.
    // Same-wave write->read; no barrier needed.
    float* wpw = &wpe[wv * NEMB];
    {
        const int e = lane & 31;
        const float2* rp = reinterpret_cast<const float2*>(recvW + e * ND + NATTN);
        float acc = 0.f;
#pragma unroll
        for (int p2 = 0; p2 < 8; ++p2) {
            float2 w = rp[p2];
            acc += w.x * pe[2 * p2];
            acc += w.y * pe[2 * p2 + 1];
        }
        if (lane < NEMB) wpw[e] = acc;
    }

    // per-lane inputs (coalesced: 64 lanes x 16B contiguous)
    const float4 xv = *reinterpret_cast<const float4*>(x + ((size_t)bt * NS + s) * NOBS);
    const float  mv = mask[(size_t)bt * NS + s];

    __syncthreads();  // obsW tile ready — the ONLY barrier in the kernel

    // hq[a] = recv_b[a] + sum_e h_e * recv_W[e][a]   (a = 0..9 only)
    // beta' = sum_e h_e * w_pe[e]
    float hq[NATTN];
#pragma unroll
    for (int a = 0; a < NATTN; ++a) hq[a] = recvB[a];  // uniform -> s_load
    float betah = 0.f;

#pragma unroll
    for (int eb = 0; eb < 8; ++eb) {  // e = eb*4 + j
        float a0 = 0.f, a1 = 0.f, a2 = 0.f, a3 = 0.f;
        {
            float4 w0 = *reinterpret_cast<const float4*>(&obsw_lds[obs_idx(s, 0 * 8 + eb)]);
            a0 += xv.x * w0.x; a1 += xv.x * w0.y; a2 += xv.x * w0.z; a3 += xv.x * w0.w;
            float4 w1 = *reinterpret_cast<const float4*>(&obsw_lds[obs_idx(s, 1 * 8 + eb)]);
            a0 += xv.y * w1.x; a1 += xv.y * w1.y; a2 += xv.y * w1.z; a3 += xv.y * w1.w;
            float4 w2 = *reinterpret_cast<const float4*>(&obsw_lds[obs_idx(s, 2 * 8 + eb)]);
            a0 += xv.z * w2.x; a1 += xv.z * w2.y; a2 += xv.z * w2.z; a3 += xv.z * w2.w;
            float4 w3 = *reinterpret_cast<const float4*>(&obsw_lds[obs_idx(s, 3 * 8 + eb)]);
            a0 += xv.w * w3.x; a1 += xv.w * w3.y; a2 += xv.w * w3.z; a3 += xv.w * w3.w;
        }
        const float h0 = fmaxf(a0, 0.f) * mv;
        const float h1 = fmaxf(a1, 0.f) * mv;
        const float h2 = fmaxf(a2, 0.f) * mv;
        const float h3 = fmaxf(a3, 0.f) * mv;

        // beta' contribution: uniform ds_read_b128 broadcast of 4 w_pe
        float4 wp = *reinterpret_cast<const float4*>(wpw + eb * 4);
        betah += h0 * wp.x + h1 * wp.y + h2 * wp.z + h3 * wp.w;

        const float* rw = recvW + (eb * 4) * ND;  // uniform base -> s_load
#pragma unroll
        for (int a = 0; a < NATTN; ++a) {
            hq[a] += h0 * rw[a] + h1 * rw[ND + a] + h2 * rw[2 * ND + a] + h3 * rw[3 * ND + a];
        }
    }

    const float beta = c0 + betah;

    // Stage this wave's hq row packed f16 (+f32 beta), 32B stride, into the
    // SEPARATE hq16 region. Same-wave write->read; NO barrier.
    unsigned* hbase = &hq16[wv * (NS * 8)];
    {
        unsigned* hrow = hbase + s * 8;
        uint4 rA;
        rA.x = pkh(hq[0], hq[1]); rA.y = pkh(hq[2], hq[3]);
        rA.z = pkh(hq[4], hq[5]); rA.w = pkh(hq[6], hq[7]);
        uint2 rB;
        rB.x = pkh(hq[8], hq[9]);
        rB.y = __builtin_bit_cast(unsigned, beta);
        *reinterpret_cast<uint4*>(hrow)     = rA;
        *reinterpret_cast<uint2*>(hrow + 4) = rB;
    }

    // Phase 3: 4 row-groups x 16 lanes (R8 grouping). Per iter: b128 + b64 at
    // 4 distinct 32B-strided addrs (bank-quads {0,8,16,24} / {4,12,20,28}:
    // conflict-free broadcast), 12 cvt + 40 FMA per lane, one coalesced 1KB
    // wave store (4 rows x 256B).
    const unsigned* hg = hbase + g * 8;
    float* optr = out + (size_t)bt * (NS * NS) + g * NS + iu * 4;
#pragma unroll 4
    for (int r = 0; r < NS; r += 4) {
        const unsigned* hr = hg + r * 8;
        uint4 A = *reinterpret_cast<const uint4*>(hr);
        uint2 Bv = *reinterpret_cast<const uint2*>(hr + 4);
        float2 q01 = unpack_h2(A.x);
        float2 q23 = unpack_h2(A.y);
        float2 q45 = unpack_h2(A.z);
        float2 q67 = unpack_h2(A.w);
        float2 q89 = unpack_h2(Bv.x);
        const float beta_r = __builtin_bit_cast(float, Bv.y);
        float acc0 = beta_r, acc1 = beta_r, acc2 = beta_r, acc3 = beta_r;
        acc0 += q01.x * aw0[0]; acc1 += q01.x * aw1[0]; acc2 += q01.x * aw2[0]; acc3 += q01.x * aw3[0];
        acc0 += q01.y * aw0[1]; acc1 += q01.y * aw1[1]; acc2 += q01.y * aw2[1]; acc3 += q01.y * aw3[1];
        acc0 += q23.x * aw0[2]; acc1 += q23.x * aw1[2]; acc2 += q23.x * aw2[2]; acc3 += q23.x * aw3[2];
        acc0 += q23.y * aw0[3]; acc1 += q23.y * aw1[3]; acc2 += q23.y * aw2[3]; acc3 += q23.y * aw3[3];
        acc0 += q45.x * aw0[4]; acc1 += q45.x * aw1[4]; acc2 += q45.x * aw2[4]; acc3 += q45.x * aw3[4];
        acc0 += q45.y * aw0[5]; acc1 += q45.y * aw1[5]; acc2 += q45.y * aw2[5]; acc3 += q45.y * aw3[5];
        acc0 += q67.x * aw0[6]; acc1 += q67.x * aw1[6]; acc2 += q67.x * aw2[6]; acc3 += q67.x * aw3[6];
        acc0 += q67.y * aw0[7]; acc1 += q67.y * aw1[7]; acc2 += q67.y * aw2[7]; acc3 += q67.y * aw3[7];
        acc0 += q89.x * aw0[8]; acc1 += q89.x * aw1[8]; acc2 += q89.x * aw2[8]; acc3 += q89.x * aw3[8];
        acc0 += q89.y * aw0[9]; acc1 += q89.y * aw1[9]; acc2 += q89.y * aw2[9]; acc3 += q89.y * aw3[9];
        float4 rv;
        rv.x = fmaxf(acc0, 0.f);
        rv.y = fmaxf(acc1, 0.f);
        rv.z = fmaxf(acc2, 0.f);
        rv.w = fmaxf(acc3, 0.f);
        *reinterpret_cast<float4*>(optr) = rv;
        optr += 4 * NS;
    }
}

extern "C" void kernel_launch(void* const* d_in, const int* in_sizes, int n_in,
                              void* d_out, int out_size, void* d_ws, size_t ws_size,
                              hipStream_t stream) {
    const float* x     = (const float*)d_in[0];
    const float* times = (const float*)d_in[1];
    const float* mask  = (const float*)d_in[2];
    const float* obsW  = (const float*)d_in[3];
    const float* attnW = (const float*)d_in[4];
    const float* recvW = (const float*)d_in[5];
    const float* recvB = (const float*)d_in[6];
    float* out = (float*)d_out;

    // B*T = 16384 (b,t) pairs, one wave each, 8 waves per block
    raindrop_kernel<<<dim3((NB * NT) / 8), dim3(512), 0, stream>>>(
        x, times, mask, obsW, attnW, recvW, recvB, out);
}